// Round 1
// baseline (37.547 us; speedup 1.0000x reference)
//
#include <hip/hip_runtime.h>
#include <math.h>

#define DD 1024
#define BB 8192

__device__ __forceinline__ float softplus_f(float x) {
    // stable log1p(exp(x))
    return fmaxf(x, 0.0f) + log1pf(expf(-fabsf(x)));
}

// ---------------- kernel A: t[j] = sum_i softplus(rho[i,j]) * eps[i] ----------
__global__ __launch_bounds__(256) void k_teps(const float* __restrict__ rho,
                                              const float* __restrict__ eps,
                                              float* __restrict__ t) {
    int j  = blockIdx.x * 256 + threadIdx.x;   // gridDim.x = 4
    int i0 = blockIdx.y * 16;                  // gridDim.y = 64
    float acc = 0.f;
#pragma unroll
    for (int k = 0; k < 16; ++k) {
        int i = i0 + k;
        acc += softplus_f(rho[i * DD + j]) * eps[i];
    }
    atomicAdd(&t[j], acc);
}

// ---------------- kernel B: u[i] = mu[i] + sum_j softplus(rho[i,j]) * t[j] ----
__global__ __launch_bounds__(256) void k_u(const float* __restrict__ rho,
                                           const float* __restrict__ mu,
                                           const float* __restrict__ t,
                                           float* __restrict__ u) {
    int i  = blockIdx.x;      // 1024 blocks
    int tx = threadIdx.x;
    float acc = 0.f;
#pragma unroll
    for (int c = 0; c < 4; ++c) {
        int j = tx + c * 256;
        acc += softplus_f(rho[i * DD + j]) * t[j];
    }
#pragma unroll
    for (int off = 32; off > 0; off >>= 1)
        acc += __shfl_down(acc, off, 64);
    __shared__ float red[4];
    int lane = tx & 63, w = tx >> 6;
    if (lane == 0) red[w] = acc;
    __syncthreads();
    if (tx == 0) u[i] = mu[i] + red[0] + red[1] + red[2] + red[3];
}

// ---------------- main: out[d,b] = relu(s1*FWHT(u*FWHT(s2*x_b))/1024) ---------

template <int CTRL>
__device__ __forceinline__ float dppmov(float x) {
    return __int_as_float(
        __builtin_amdgcn_mov_dpp(__float_as_int(x), CTRL, 0xF, 0xF, true));
}

// Position mapping: lane l (bits l0..l5), reg m (4 bits). p = 16*hi(l) + m with
//   h0=l0^l2  h1=l1^l2  h2=l2^l3  h3=l3  h4=l4  h5=l5
// so flipping position bits p4..p9 corresponds to lane XOR masks
//   1 (quad_perm), 2 (quad_perm), 7 (row_half_mirror), 15 (row_mirror), 16, 32.
__device__ __forceinline__ void fwht1024(float v[16], float sA, float sB,
                                         float sC, float sD, float sE, float sF) {
    // in-register stages: position bits p0..p3 (strides 1,2,4,8 in m)
#pragma unroll
    for (int s = 1; s <= 8; s <<= 1) {
#pragma unroll
        for (int m = 0; m < 16; ++m)
            if ((m & s) == 0) {
                float a = v[m], b = v[m ^ s];
                v[m] = a + b;
                v[m ^ s] = a - b;
            }
    }
    // cross-lane stages: out = own*sgn + partner  (sgn = position-bit ? -1 : +1)
#pragma unroll
    for (int m = 0; m < 16; ++m) { float o = dppmov<0xB1>(v[m]);  v[m] = fmaf(v[m], sA, o); } // xor 1
#pragma unroll
    for (int m = 0; m < 16; ++m) { float o = dppmov<0x4E>(v[m]);  v[m] = fmaf(v[m], sB, o); } // xor 2
#pragma unroll
    for (int m = 0; m < 16; ++m) { float o = dppmov<0x141>(v[m]); v[m] = fmaf(v[m], sC, o); } // xor 7
#pragma unroll
    for (int m = 0; m < 16; ++m) { float o = dppmov<0x140>(v[m]); v[m] = fmaf(v[m], sD, o); } // xor 15
#pragma unroll
    for (int m = 0; m < 16; ++m) { float o = __shfl_xor(v[m], 16, 64); v[m] = fmaf(v[m], sE, o); } // xor 16
#pragma unroll
    for (int m = 0; m < 16; ++m) { float o = __shfl_xor(v[m], 32, 64); v[m] = fmaf(v[m], sF, o); } // xor 32
}

__global__ __launch_bounds__(512) void k_main(const float* __restrict__ x,
                                              const float* __restrict__ s1,
                                              const float* __restrict__ s2,
                                              const float* __restrict__ u,
                                              float* __restrict__ out) {
    __shared__ float tile[16 * 1024];   // 64 KB: 16 batch rows, XOR-swizzled
    const int t    = threadIdx.x;
    const int lane = t & 63;
    const int wv   = t >> 6;            // 0..7
    const int b0   = blockIdx.x * 16;   // 512 blocks

    const int l0 = lane & 1, l1 = (lane >> 1) & 1, l2 = (lane >> 2) & 1,
              l3 = (lane >> 3) & 1, l4 = (lane >> 4) & 1, l5 = (lane >> 5) & 1;
    const int hi = (l0 ^ l2) | ((l1 ^ l2) << 1) | ((l2 ^ l3) << 2) | (l3 << 3) |
                   (l4 << 4) | (l5 << 5);
    const int base = hi << 4;           // this lane's 16 contiguous elements

    const float sA = (l0 ^ l2) ? -1.f : 1.f;
    const float sB = (l1 ^ l2) ? -1.f : 1.f;
    const float sC = (l2 ^ l3) ? -1.f : 1.f;
    const float sD = l3 ? -1.f : 1.f;
    const float sE = l4 ? -1.f : 1.f;
    const float sF = l5 ? -1.f : 1.f;

    // hoisted scale fragments (L2-resident, read once per wave)
    float4 s2f[4], uf[4], s1f[4];
#pragma unroll
    for (int c = 0; c < 4; ++c) {
        s2f[c] = *(const float4*)(s2 + base + 4 * c);
        uf[c]  = *(const float4*)(u  + base + 4 * c);
        s1f[c] = *(const float4*)(s1 + base + 4 * c);
    }
    const int swz = (lane >> 1) & 15;   // bank-spread XOR for LDS writes

    for (int rr = 0; rr < 2; ++rr) {
        const int r = wv * 2 + rr;      // row in tile (= batch b0+r)
        const float* xr = x + (b0 + r) * DD + base;
        float v[16];
#pragma unroll
        for (int c = 0; c < 4; ++c) {
            float4 xv = *(const float4*)(xr + 4 * c);
            v[4 * c + 0] = xv.x * s2f[c].x;
            v[4 * c + 1] = xv.y * s2f[c].y;
            v[4 * c + 2] = xv.z * s2f[c].z;
            v[4 * c + 3] = xv.w * s2f[c].w;
        }
        fwht1024(v, sA, sB, sC, sD, sE, sF);
#pragma unroll
        for (int c = 0; c < 4; ++c) {
            v[4 * c + 0] *= uf[c].x;
            v[4 * c + 1] *= uf[c].y;
            v[4 * c + 2] *= uf[c].z;
            v[4 * c + 3] *= uf[c].w;
        }
        fwht1024(v, sA, sB, sC, sD, sE, sF);
        const float kscale = 1.0f / 1024.0f;
        float* trow = tile + r * 1024 + base;
        const int sw2 = (swz ^ r) & 15;
#pragma unroll
        for (int c = 0; c < 4; ++c) {
            float y0 = fmaxf(v[4 * c + 0] * s1f[c].x * kscale, 0.f);
            float y1 = fmaxf(v[4 * c + 1] * s1f[c].y * kscale, 0.f);
            float y2 = fmaxf(v[4 * c + 2] * s1f[c].z * kscale, 0.f);
            float y3 = fmaxf(v[4 * c + 3] * s1f[c].w * kscale, 0.f);
            trow[(4 * c + 0) ^ sw2] = y0;
            trow[(4 * c + 1) ^ sw2] = y1;
            trow[(4 * c + 2) ^ sw2] = y2;
            trow[(4 * c + 3) ^ sw2] = y3;
        }
    }
    __syncthreads();

    // transposed store: thread t -> batch col r = t&15 (64B-contiguous lines)
#pragma unroll
    for (int it = 0; it < 32; ++it) {
        int d = (t >> 4) + (it << 5);   // output feature index
        int r = t & 15;
        int h  = d >> 4;
        int h1 = (h >> 1) & 1, h2 = (h >> 2) & 1, h3 = (h >> 3) & 1,
            h4 = (h >> 4) & 1;
        // recompute writer lane's swizzle from position bits
        int sw = (h1 ^ h2 ^ h3) | ((h2 ^ h3) << 1) | (h3 << 2) | (h4 << 3);
        float y = tile[r * 1024 + (d & ~15) + (((d & 15) ^ sw ^ r) & 15)];
        out[d * BB + b0 + r] = y;
    }
}

extern "C" void kernel_launch(void* const* d_in, const int* in_sizes, int n_in,
                              void* d_out, int out_size, void* d_ws, size_t ws_size,
                              hipStream_t stream) {
    const float* x   = (const float*)d_in[0];
    const float* s1  = (const float*)d_in[1];
    const float* s2  = (const float*)d_in[2];
    const float* mu  = (const float*)d_in[3];
    const float* rho = (const float*)d_in[4];
    const float* eps = (const float*)d_in[5];
    // d_in[6] = H is unused: we apply it via fast Walsh-Hadamard transform.
    float* out = (float*)d_out;

    float* t = (float*)d_ws;   // [DD]
    float* u = t + DD;         // [DD]

    hipMemsetAsync(t, 0, DD * sizeof(float), stream);

    dim3 gA(4, 64);
    k_teps<<<gA, 256, 0, stream>>>(rho, eps, t);
    k_u<<<DD, 256, 0, stream>>>(rho, mu, t, u);
    k_main<<<BB / 16, 512, 0, stream>>>(x, s1, s2, u, out);
}

// Round 2
// 34.812 us; speedup vs baseline: 1.0786x; 1.0786x over previous
//
#include <hip/hip_runtime.h>
#include <math.h>

#define DD 1024
#define BB 8192

__device__ __forceinline__ float softplus_f(float x) {
    // stable log1p(exp(x))
    return fmaxf(x, 0.0f) + log1pf(expf(-fabsf(x)));
}

// ---------------- kernel A: t[j] = sum_i softplus(rho[i,j]) * eps[i] ----------
// One block per column j. Strided reads are L2-absorbed (rho = 4 MB total,
// each 64B line is shared by 16 adjacent-j blocks). No atomics, no memset.
__global__ __launch_bounds__(256) void k_t(const float* __restrict__ rho,
                                           const float* __restrict__ eps,
                                           float* __restrict__ t) {
    int j  = blockIdx.x;      // 1024 blocks
    int tx = threadIdx.x;
    float acc = 0.f;
#pragma unroll
    for (int c = 0; c < 4; ++c) {
        int i = tx + c * 256;
        acc += softplus_f(rho[i * DD + j]) * eps[i];
    }
#pragma unroll
    for (int off = 32; off > 0; off >>= 1)
        acc += __shfl_down(acc, off, 64);
    __shared__ float red[4];
    int lane = tx & 63, w = tx >> 6;
    if (lane == 0) red[w] = acc;
    __syncthreads();
    if (tx == 0) t[j] = red[0] + red[1] + red[2] + red[3];
}

// ---------------- kernel B: u[i] = mu[i] + sum_j softplus(rho[i,j]) * t[j] ----
__global__ __launch_bounds__(256) void k_u(const float* __restrict__ rho,
                                           const float* __restrict__ mu,
                                           const float* __restrict__ t,
                                           float* __restrict__ u) {
    int i  = blockIdx.x;      // 1024 blocks
    int tx = threadIdx.x;
    float acc = 0.f;
#pragma unroll
    for (int c = 0; c < 4; ++c) {
        int j = tx + c * 256;
        acc += softplus_f(rho[i * DD + j]) * t[j];
    }
#pragma unroll
    for (int off = 32; off > 0; off >>= 1)
        acc += __shfl_down(acc, off, 64);
    __shared__ float red[4];
    int lane = tx & 63, w = tx >> 6;
    if (lane == 0) red[w] = acc;
    __syncthreads();
    if (tx == 0) u[i] = mu[i] + red[0] + red[1] + red[2] + red[3];
}

// ---------------- main: out[d,b] = relu(s1*FWHT(u*FWHT(s2*x_b))/1024) ---------

template <int CTRL>
__device__ __forceinline__ float dppmov(float x) {
    return __int_as_float(
        __builtin_amdgcn_mov_dpp(__float_as_int(x), CTRL, 0xF, 0xF, true));
}

// Position mapping: lane l (bits l0..l5), reg m (4 bits). p = 16*hi(l) + m with
//   h0=l0^l2  h1=l1^l2  h2=l2^l3  h3=l3  h4=l4  h5=l5
// so flipping position bits p4..p9 corresponds to lane XOR masks
//   1 (quad_perm), 2 (quad_perm), 7 (row_half_mirror), 15 (row_mirror), 16, 32.
__device__ __forceinline__ void fwht1024(float v[16], float sA, float sB,
                                         float sC, float sD, float sE, float sF) {
    // in-register stages: position bits p0..p3 (strides 1,2,4,8 in m)
#pragma unroll
    for (int s = 1; s <= 8; s <<= 1) {
#pragma unroll
        for (int m = 0; m < 16; ++m)
            if ((m & s) == 0) {
                float a = v[m], b = v[m ^ s];
                v[m] = a + b;
                v[m ^ s] = a - b;
            }
    }
    // cross-lane stages: out = own*sgn + partner  (sgn = position-bit ? -1 : +1)
#pragma unroll
    for (int m = 0; m < 16; ++m) { float o = dppmov<0xB1>(v[m]);  v[m] = fmaf(v[m], sA, o); } // xor 1
#pragma unroll
    for (int m = 0; m < 16; ++m) { float o = dppmov<0x4E>(v[m]);  v[m] = fmaf(v[m], sB, o); } // xor 2
#pragma unroll
    for (int m = 0; m < 16; ++m) { float o = dppmov<0x141>(v[m]); v[m] = fmaf(v[m], sC, o); } // xor 7
#pragma unroll
    for (int m = 0; m < 16; ++m) { float o = dppmov<0x140>(v[m]); v[m] = fmaf(v[m], sD, o); } // xor 15
#pragma unroll
    for (int m = 0; m < 16; ++m) { float o = __shfl_xor(v[m], 16, 64); v[m] = fmaf(v[m], sE, o); } // xor 16
#pragma unroll
    for (int m = 0; m < 16; ++m) { float o = __shfl_xor(v[m], 32, 64); v[m] = fmaf(v[m], sF, o); } // xor 32
}

__global__ __launch_bounds__(512) void k_main(const float* __restrict__ x,
                                              const float* __restrict__ s1,
                                              const float* __restrict__ s2,
                                              const float* __restrict__ u,
                                              float* __restrict__ out) {
    __shared__ float tile[16 * 1024];   // 64 KB: 16 batch rows, XOR-swizzled
    const int t    = threadIdx.x;
    const int lane = t & 63;
    const int wv   = t >> 6;            // 0..7
    const int b0   = blockIdx.x * 16;   // 512 blocks

    const int l0 = lane & 1, l1 = (lane >> 1) & 1, l2 = (lane >> 2) & 1,
              l3 = (lane >> 3) & 1, l4 = (lane >> 4) & 1, l5 = (lane >> 5) & 1;
    const int hi = (l0 ^ l2) | ((l1 ^ l2) << 1) | ((l2 ^ l3) << 2) | (l3 << 3) |
                   (l4 << 4) | (l5 << 5);
    const int base = hi << 4;           // this lane's 16 contiguous elements

    const float sA = (l0 ^ l2) ? -1.f : 1.f;
    const float sB = (l1 ^ l2) ? -1.f : 1.f;
    const float sC = (l2 ^ l3) ? -1.f : 1.f;
    const float sD = l3 ? -1.f : 1.f;
    const float sE = l4 ? -1.f : 1.f;
    const float sF = l5 ? -1.f : 1.f;

    // hoisted scale fragments (L2-resident, read once per wave)
    float4 s2f[4], uf[4], s1f[4];
#pragma unroll
    for (int c = 0; c < 4; ++c) {
        s2f[c] = *(const float4*)(s2 + base + 4 * c);
        uf[c]  = *(const float4*)(u  + base + 4 * c);
        s1f[c] = *(const float4*)(s1 + base + 4 * c);
        const float kscale = 1.0f / 1024.0f;   // fold 1/D into s1
        s1f[c].x *= kscale; s1f[c].y *= kscale;
        s1f[c].z *= kscale; s1f[c].w *= kscale;
    }
    const int swz = (lane >> 1) & 15;   // bank-spread XOR for LDS writes

    // hoist both batch-row loads for latency hiding
    const int r0 = wv * 2;
    const int r1 = r0 + 1;
    const float* xr0 = x + (size_t)(b0 + r0) * DD + base;
    const float* xr1 = xr0 + DD;
    float va[16], vb[16];
#pragma unroll
    for (int c = 0; c < 4; ++c) {
        float4 xv0 = *(const float4*)(xr0 + 4 * c);
        float4 xv1 = *(const float4*)(xr1 + 4 * c);
        va[4 * c + 0] = xv0.x * s2f[c].x;  vb[4 * c + 0] = xv1.x * s2f[c].x;
        va[4 * c + 1] = xv0.y * s2f[c].y;  vb[4 * c + 1] = xv1.y * s2f[c].y;
        va[4 * c + 2] = xv0.z * s2f[c].z;  vb[4 * c + 2] = xv1.z * s2f[c].z;
        va[4 * c + 3] = xv0.w * s2f[c].w;  vb[4 * c + 3] = xv1.w * s2f[c].w;
    }

#pragma unroll
    for (int rr = 0; rr < 2; ++rr) {
        const int r = (rr == 0) ? r0 : r1;
        float* v = (rr == 0) ? va : vb;
        fwht1024(v, sA, sB, sC, sD, sE, sF);
#pragma unroll
        for (int c = 0; c < 4; ++c) {
            v[4 * c + 0] *= uf[c].x;
            v[4 * c + 1] *= uf[c].y;
            v[4 * c + 2] *= uf[c].z;
            v[4 * c + 3] *= uf[c].w;
        }
        fwht1024(v, sA, sB, sC, sD, sE, sF);
        // LDS layout for (row r, feature d = hi*16 + m):
        //   col = ((hi ^ ((r>>2)&3)) << 4) | ((m ^ swz(hi) ^ r) & 15)
        // bijective per row; write AND read are both <=2-way bank aliased (free)
        float* trow = tile + r * 1024;
        const int baseW = ((hi ^ ((r >> 2) & 3)) << 4);
        const int sw2 = (swz ^ r) & 15;
#pragma unroll
        for (int c = 0; c < 4; ++c) {
            float y0 = fmaxf(v[4 * c + 0] * s1f[c].x, 0.f);
            float y1 = fmaxf(v[4 * c + 1] * s1f[c].y, 0.f);
            float y2 = fmaxf(v[4 * c + 2] * s1f[c].z, 0.f);
            float y3 = fmaxf(v[4 * c + 3] * s1f[c].w, 0.f);
            trow[baseW + ((4 * c + 0) ^ sw2)] = y0;
            trow[baseW + ((4 * c + 1) ^ sw2)] = y1;
            trow[baseW + ((4 * c + 2) ^ sw2)] = y2;
            trow[baseW + ((4 * c + 3) ^ sw2)] = y3;
        }
    }
    __syncthreads();

    // transposed store: thread t -> feature d = (t>>2)+it*128, batches r4..r4+3
    // (4 lanes x float4 = 64B contiguous per feature row)
#pragma unroll
    for (int it = 0; it < 8; ++it) {
        const int d  = (t >> 2) + (it << 7);
        const int r4 = (t & 3) << 2;
        const int q  = t & 3;           // == (r>>2) for all 4 rows of this thread
        const int h  = d >> 4;
        const int dl = d & 15;
        const int h1 = (h >> 1) & 1, h2 = (h >> 2) & 1, h3 = (h >> 3) & 1,
                  h4 = (h >> 4) & 1;
        // writer lane's swz reconstructed from position bits of h
        const int sw = (h1 ^ h2 ^ h3) | ((h2 ^ h3) << 1) | (h3 << 2) | (h4 << 3);
        const int colhi = (h ^ q) << 4;
        float4 y;
        y.x = tile[(r4 + 0) * 1024 + colhi + ((dl ^ sw ^ (r4 + 0)) & 15)];
        y.y = tile[(r4 + 1) * 1024 + colhi + ((dl ^ sw ^ (r4 + 1)) & 15)];
        y.z = tile[(r4 + 2) * 1024 + colhi + ((dl ^ sw ^ (r4 + 2)) & 15)];
        y.w = tile[(r4 + 3) * 1024 + colhi + ((dl ^ sw ^ (r4 + 3)) & 15)];
        *(float4*)(out + (size_t)d * BB + b0 + r4) = y;
    }
}

extern "C" void kernel_launch(void* const* d_in, const int* in_sizes, int n_in,
                              void* d_out, int out_size, void* d_ws, size_t ws_size,
                              hipStream_t stream) {
    const float* x   = (const float*)d_in[0];
    const float* s1  = (const float*)d_in[1];
    const float* s2  = (const float*)d_in[2];
    const float* mu  = (const float*)d_in[3];
    const float* rho = (const float*)d_in[4];
    const float* eps = (const float*)d_in[5];
    // d_in[6] = H is unused: we apply it via fast Walsh-Hadamard transform.
    float* out = (float*)d_out;

    float* t = (float*)d_ws;   // [DD]
    float* u = t + DD;         // [DD]

    k_t<<<DD, 256, 0, stream>>>(rho, eps, t);
    k_u<<<DD, 256, 0, stream>>>(rho, mu, t, u);
    k_main<<<BB / 16, 512, 0, stream>>>(x, s1, s2, u, out);
}